// Round 5
// baseline (362.588 us; speedup 1.0000x reference)
//
#include <hip/hip_runtime.h>
#include <stdint.h>

#define HH 80
#define WW 80
#define CC 64
#define BB 32
#define NDIAG (HH + WW - 1)   // 159
#define SLICE (HH * WW * CC)  // 409600 f16 per (dir,b) scratch slice

typedef _Float16 f16;
typedef _Float16 f16x8 __attribute__((ext_vector_type(8)));
typedef _Float16 f16x4 __attribute__((ext_vector_type(4)));
typedef float floatx4 __attribute__((ext_vector_type(4)));

struct GPtrs { const float* p[8]; };

// ---------------------------------------------------------------------------
// Pre-pass: x[b][c][i][j] (f32) -> xT[((b*H+i)*W+j)*C + c] (f16).
// LDS tile stride 65 dwords -> bank = (j + c) mod 32: stage-1 writes and
// stage-2 column reads both conflict-free (<=2-way).
// ---------------------------------------------------------------------------
__global__ __launch_bounds__(256) void xpose_kernel(const float* __restrict__ x,
                                                    f16* __restrict__ xT) {
  const int bi = blockIdx.x;            // b*HH + i
  const int b = bi / HH, i = bi - b * HH;
  __shared__ float tile[WW][CC + 1];    // [j][c], stride 65
  const float* xp = x + ((size_t)(b * CC) * HH + i) * WW;  // + c*(H*W) + j
  for (int idx = threadIdx.x; idx < CC * WW; idx += 256) {
    const int c = idx / WW, j = idx - c * WW;   // consecutive j -> coalesced reads
    tile[j][c] = xp[(size_t)c * (HH * WW) + j];
  }
  __syncthreads();
  f16* op = xT + (size_t)(b * HH + i) * WW * CC;
  for (int idx = threadIdx.x; idx < (WW * CC) / 4; idx += 256) {
    const int j = idx >> 4, m = idx & 15;       // 16 lanes cover one j
    f16x4 v;
    v[0] = (f16)tile[j][m * 4 + 0];
    v[1] = (f16)tile[j][m * 4 + 1];
    v[2] = (f16)tile[j][m * 4 + 2];
    v[3] = (f16)tile[j][m * 4 + 3];
    *(f16x4*)(op + j * CC + m * 4) = v;         // 128B contiguous per 16 lanes
  }
}

// ---------------------------------------------------------------------------
// Main kernel, CELL-SPLIT: one block per (dir,b) = 128 blocks, 4 waves.
// Wave w owns cell tiles t with t%4==w (<=2 tiles/diag) and computes ALL 64
// output channels for its cells: B fragments are read from LDS ONCE per tile
// (20 ds_read_b128/diag aggregate, was 80 when every wave re-read every tile).
// A fragments for all 4 channel-blocks live in VGPRs. MFMA C is seeded with x
// (D = A*B + C) to kill the epilogue add. x prefetched 2 diagonals ahead;
// scratch stores deferred 1 diagonal; lgkm-only barrier.
// ---------------------------------------------------------------------------
__global__ __launch_bounds__(256, 1) void dag_kernel(const f16* __restrict__ xT,
                                                     GPtrs g,
                                                     f16* __restrict__ scratch) {
  const int blk = blockIdx.x;   // 0..127
  const int dir = blk >> 5;     // 0:SE 1:NE 2:NW 3:SW
  const int b   = blk & 31;
  const int tid = threadIdx.x;
  const int wave = tid >> 6;    // owns tiles t == wave (mod 4)
  const int lane = tid & 63;
  const int l15  = lane & 15;   // cell-in-tile (MFMA n / C-D col)
  const int quad = lane >> 4;   // k-quad for A/B, row-quad for C/D

  const bool fi      = (dir == 1) || (dir == 2);  // flip i
  const bool fj      = (dir == 2) || (dir == 3);  // flip j
  const bool do_relu = (dir != 3);                // SW scan has no ReLU
  const float* __restrict__ gv = g.p[2 * dir];
  const float* __restrict__ gh = g.p[2 * dir + 1];

  // [parity][s][c]: s = i'+1; s=0 is the i'=-1 zero guard, s=81 the top guard.
  __shared__ f16 hbuf[2][HH + 2][CC + 8];
  for (int idx = tid; idx < 2 * (HH + 2) * (CC + 8); idx += 256)
    (&hbuf[0][0][0])[idx] = (f16)0.0f;

  // A fragments for ALL 4 channel blocks: A[m][k], m = l15, k = quad*8 + jj.
  f16x8 Av[4][2], Ah[4][2];
#pragma unroll
  for (int cb = 0; cb < 4; ++cb) {
    const int row = cb * 16 + l15;
    const float* pv = gv + row * CC;
    const float* ph = gh + row * CC;
#pragma unroll
    for (int jj = 0; jj < 8; ++jj) {
      Av[cb][0][jj] = (f16)pv[quad * 8 + jj];
      Av[cb][1][jj] = (f16)pv[32 + quad * 8 + jj];
      Ah[cb][0][jj] = (f16)ph[quad * 8 + jj];
      Ah[cb][1][jj] = (f16)ph[32 + quad * 8 + jj];
    }
  }
  const int cq = quad * 4;  // channel offset within a block (C/D row-quad)
  const f16* const xTb = xT + (size_t)b * SLICE;
  f16* const sbase = scratch + (size_t)blk * SLICE;

  // Prefetch x (all 4 channel blocks) for this wave's <=2 tiles of diag d1.
  auto prefetch = [&](int d1, f16x4 (*xv)[4], int* offv) {
    const int ilo1 = max(0, d1 - (WW - 1));
    const int ihi1 = min(d1, HH - 1);
#pragma unroll
    for (int s = 0; s < 2; ++s) {
      const int t = wave + 4 * s;
      const int ip1 = min(ilo1 + t * 16 + l15, ihi1);  // clamped: always valid addr
      const int jp1 = d1 - ip1;
      const int io1 = fi ? (HH - 1 - ip1) : ip1;
      const int jo1 = fj ? (WW - 1 - jp1) : jp1;
      const int off = ((io1 * WW + jo1) << 6) + cq;    // cell offset in xT/scratch
      offv[s] = off;
#pragma unroll
      for (int cb = 0; cb < 4; ++cb)
        xv[s][cb] = *(const f16x4*)(xTb + off + cb * 16);
    }
  };

  f16x4 xv0[2][4]; int off0[2];   // x for diag d   (consumed this iteration)
  f16x4 xv1[2][4]; int off1[2];   // x for diag d+1 (in flight)
  int psoff[2]; f16x4 phw[2][4];  // deferred-store state (offset <0 => dead lane)
  psoff[0] = psoff[1] = -1;
  prefetch(0, xv0, off0);
  prefetch(1, xv1, off1);

  __syncthreads();  // zero-init + A-frags visible before first diagonal

  for (int d = 0; d < NDIAG; ++d) {
    const int p = d & 1, q = p ^ 1;
    const int ilo = max(0, d - (WW - 1));
    const int ihi = min(d, HH - 1);
    const int ntiles = ((ihi - ilo) >> 4) + 1;

    // 1. flush previous diagonal's scratch stores (acks never drained)
#pragma unroll
    for (int s = 0; s < 2; ++s)
      if (psoff[s] >= 0) {
#pragma unroll
        for (int cb = 0; cb < 4; ++cb)
          *(f16x4*)(sbase + psoff[s] + cb * 16) = phw[s][cb];
      }

    // 2. prefetch x for diag d+2
    f16x4 nxv[2][4]; int noff[2];
    prefetch(min(d + 2, NDIAG - 1), nxv, noff);

    const f16 (* __restrict__ hq)[CC + 8] = hbuf[q];
    f16 (* __restrict__ hp)[CC + 8] = hbuf[p];

    // 3. this wave's owned tiles: read B once, 16 MFMAs, epilogue, writes.
#pragma unroll
    for (int s = 0; s < 2; ++s) {
      const int t = wave + 4 * s;
      if (t < ntiles) {                       // wave-uniform branch
        const int ip = ilo + t * 16 + l15;
        const int su = min(ip, HH + 1);       // up   (i'-1,j') -> s=i'
        const int sl = min(ip + 1, HH + 1);   // left (i',j'-1) -> s=i'+1
        const f16x8 bu0 = *(const f16x8*)&hq[su][quad * 8];
        const f16x8 bu1 = *(const f16x8*)&hq[su][32 + quad * 8];
        const f16x8 bl0 = *(const f16x8*)&hq[sl][quad * 8];
        const f16x8 bl1 = *(const f16x8*)&hq[sl][32 + quad * 8];
        const bool ok = (ip <= ihi);          // dead lanes' garbage stays in col l15
#pragma unroll
        for (int cb = 0; cb < 4; ++cb) {
          floatx4 a;
          a[0] = (float)xv0[s][cb][0];        // seed C with x: D = gv@up + gh@left + x
          a[1] = (float)xv0[s][cb][1];
          a[2] = (float)xv0[s][cb][2];
          a[3] = (float)xv0[s][cb][3];
          a = __builtin_amdgcn_mfma_f32_16x16x32_f16(Av[cb][0], bu0, a, 0, 0, 0);
          a = __builtin_amdgcn_mfma_f32_16x16x32_f16(Av[cb][1], bu1, a, 0, 0, 0);
          a = __builtin_amdgcn_mfma_f32_16x16x32_f16(Ah[cb][0], bl0, a, 0, 0, 0);
          a = __builtin_amdgcn_mfma_f32_16x16x32_f16(Ah[cb][1], bl1, a, 0, 0, 0);
          float h0 = a[0], h1 = a[1], h2 = a[2], h3 = a[3];
          if (do_relu) {
            h0 = fmaxf(h0, 0.f); h1 = fmaxf(h1, 0.f);
            h2 = fmaxf(h2, 0.f); h3 = fmaxf(h3, 0.f);
          }
          f16x4 hw;
          hw[0] = (f16)h0; hw[1] = (f16)h1; hw[2] = (f16)h2; hw[3] = (f16)h3;
          if (ok) *(f16x4*)&hp[ip + 1][cb * 16 + cq] = hw;
          phw[s][cb] = hw;
        }
        psoff[s] = ok ? off0[s] : -1;
      } else {
        psoff[s] = -1;
      }
    }

    // rotate the two-deep prefetch pipeline
#pragma unroll
    for (int s = 0; s < 2; ++s) {
      off0[s] = off1[s]; off1[s] = noff[s];
#pragma unroll
      for (int cb = 0; cb < 4; ++cb) { xv0[s][cb] = xv1[s][cb]; xv1[s][cb] = nxv[s][cb]; }
    }

    // Raw barrier: drain LDS only (lgkmcnt(0)); vmem stays in flight.
    __builtin_amdgcn_s_waitcnt(0xC07F);  // vmcnt(63) expcnt(7) lgkmcnt(0)
    __builtin_amdgcn_s_barrier();
  }

  // final flush (last diagonal's deferred stores)
#pragma unroll
  for (int s = 0; s < 2; ++s)
    if (psoff[s] >= 0) {
#pragma unroll
      for (int cb = 0; cb < 4; ++cb)
        *(f16x4*)(sbase + psoff[s] + cb * 16) = phw[s][cb];
    }
}

// ---------------------------------------------------------------------------
// Reduce: out[b][c][i][j] = sum over 4 dirs of scratch[dir][b][i][j][c].
// LDS stride 65 -> bank = (j + c) mod 32: stage-1 scalar writes ~free,
// stage-2 column reads ~free. Stage-2: 4-lane groups write 64B-contiguous
// float4 runs along j per channel c.
// ---------------------------------------------------------------------------
__global__ __launch_bounds__(256) void reduce_kernel(const f16* __restrict__ s,
                                                     float* __restrict__ out) {
  const int bi = blockIdx.x;            // b*HH + i
  const int b = bi / HH, i = bi - b * HH;
  __shared__ float tile[WW][CC + 1];    // [j][c], stride 65
  const size_t dstride = (size_t)BB * SLICE;
  const f16* p = s + (size_t)b * SLICE + (size_t)i * (WW * CC);
  for (int idx = threadIdx.x; idx < (WW * CC) / 8; idx += 256) {  // 640
    const int j = idx >> 3, c8 = (idx & 7) * 8;
    const size_t off = (size_t)j * CC + c8;
    const f16x8 a0 = *(const f16x8*)(p + off);
    const f16x8 a1 = *(const f16x8*)(p + off + dstride);
    const f16x8 a2 = *(const f16x8*)(p + off + 2 * dstride);
    const f16x8 a3 = *(const f16x8*)(p + off + 3 * dstride);
#pragma unroll
    for (int k = 0; k < 8; ++k)
      tile[j][c8 + k] = (float)a0[k] + (float)a1[k] + (float)a2[k] + (float)a3[k];
  }
  __syncthreads();
  float* op = out + ((size_t)(b * CC) * HH + i) * WW;  // + c*(H*W) + j
  const int c  = threadIdx.x >> 2;        // 0..63
  const int jb = (threadIdx.x & 3) * 4;   // 0,4,8,12
#pragma unroll
  for (int k = 0; k < 5; ++k) {
    const int j0 = jb + k * 16;
    floatx4 v;
    v[0] = tile[j0 + 0][c];
    v[1] = tile[j0 + 1][c];
    v[2] = tile[j0 + 2][c];
    v[3] = tile[j0 + 3][c];
    *(floatx4*)(op + (size_t)c * (HH * WW) + j0) = v;  // 64B contiguous per 4 lanes
  }
}

// ---------------------------------------------------------------------------
extern "C" void kernel_launch(void* const* d_in, const int* in_sizes, int n_in,
                              void* d_out, int out_size, void* d_ws, size_t ws_size,
                              hipStream_t stream) {
  const float* x = (const float*)d_in[0];
  GPtrs g;
  for (int k = 0; k < 8; ++k) g.p[k] = (const float*)d_in[k + 1];  // g1,g2,g4,g5,g7,g8,g10,g11
  f16* xT = (f16*)d_ws;                         // 26.2 MB
  f16* scratch = xT + (size_t)BB * SLICE;       // 104.9 MB

  xpose_kernel<<<BB * HH, 256, 0, stream>>>(x, xT);
  dag_kernel<<<4 * BB, 256, 0, stream>>>((const f16*)xT, g, scratch);
  reduce_kernel<<<BB * HH, 256, 0, stream>>>((const f16*)scratch, (float*)d_out);
}

// Round 6
// 252.407 us; speedup vs baseline: 1.4365x; 1.4365x over previous
//
#include <hip/hip_runtime.h>
#include <stdint.h>

#define HH 80
#define WW 80
#define CC 64
#define BB 32
#define NDIAG (HH + WW - 1)   // 159
#define SLICE (HH * WW * CC)  // 409600 f16 per (dir,b) scratch slice
#define NCW 5                 // compute waves (one 16-cell tile each)
#define NTHREADS 512          // 5 compute + 3 io waves

typedef _Float16 f16;
typedef _Float16 f16x8 __attribute__((ext_vector_type(8)));
typedef _Float16 f16x4 __attribute__((ext_vector_type(4)));
typedef float floatx4 __attribute__((ext_vector_type(4)));

struct GPtrs { const float* p[8]; };

// ---------------------------------------------------------------------------
// Pre-pass: x[b][c][i][j] (f32) -> xT[((b*H+i)*W+j)*C + c] (f16).
// ---------------------------------------------------------------------------
__global__ __launch_bounds__(256) void xpose_kernel(const float* __restrict__ x,
                                                    f16* __restrict__ xT) {
  const int bi = blockIdx.x;            // b*HH + i
  const int b = bi / HH, i = bi - b * HH;
  __shared__ float tile[WW][CC + 1];    // [j][c], stride 65
  const float* xp = x + ((size_t)(b * CC) * HH + i) * WW;  // + c*(H*W) + j
  for (int idx = threadIdx.x; idx < CC * WW; idx += 256) {
    const int c = idx / WW, j = idx - c * WW;   // consecutive j -> coalesced reads
    tile[j][c] = xp[(size_t)c * (HH * WW) + j];
  }
  __syncthreads();
  f16* op = xT + (size_t)(b * HH + i) * WW * CC;
  for (int idx = threadIdx.x; idx < (WW * CC) / 4; idx += 256) {
    const int j = idx >> 4, m = idx & 15;       // 16 lanes cover one j
    f16x4 v;
    v[0] = (f16)tile[j][m * 4 + 0];
    v[1] = (f16)tile[j][m * 4 + 1];
    v[2] = (f16)tile[j][m * 4 + 2];
    v[3] = (f16)tile[j][m * 4 + 3];
    *(f16x4*)(op + j * CC + m * 4) = v;         // 128B contiguous per 16 lanes
  }
}

// ---------------------------------------------------------------------------
// Main kernel, PRODUCER/CONSUMER: 128 blocks x 512 threads (8 waves).
// Waves 0..4 (compute): pure LDS+MFMA loop — ZERO vmem instructions, so no
//   vmcnt wait can ever land on the barrier-to-barrier path. Wave t owns the
//   16-cell tile t of each diagonal and computes all 64 output channels.
// Waves 5..7 (io): (a) stream x one diagonal ahead into a 2-slot LDS ring
//   (global_load -> regs -> ds_write; load latency spans a full interval),
//   (b) flush diag d-1's h from hbuf[q] (stable during interval d) to scratch.
//   All vmem latency lands on io waves, which have ~2x slack.
// Shared raw barrier: lgkmcnt(0)-only, in uniform control flow.
// ---------------------------------------------------------------------------
__global__ __launch_bounds__(NTHREADS, 1) void dag_kernel(const f16* __restrict__ xT,
                                                          GPtrs g,
                                                          f16* __restrict__ scratch) {
  const int blk = blockIdx.x;   // 0..127
  const int dir = blk >> 5;     // 0:SE 1:NE 2:NW 3:SW
  const int b   = blk & 31;
  const int tid = threadIdx.x;
  const int wv   = tid >> 6;    // 0..7
  const int lane = tid & 63;
  const int l15  = lane & 15;   // compute: cell-in-tile (MFMA n / C-D col)
  const int quad = lane >> 4;   // compute: k-quad / C-D row-quad

  const bool fi      = (dir == 1) || (dir == 2);  // flip i
  const bool fj      = (dir == 2) || (dir == 3);  // flip j
  const bool do_relu = (dir != 3);                // SW scan has no ReLU
  const float* __restrict__ gv = g.p[2 * dir];
  const float* __restrict__ gh = g.p[2 * dir + 1];

  // h state: [parity][s][c]; s=i'+1, s=0 zero guard, s=81 top guard. 144B rows.
  __align__(16) __shared__ f16 hbuf[2][HH + 2][CC + 8];   // 23,616 B
  // x ring: 2 slots, [cell i'][c]. 144B rows (b64 reads 2-way -> free).
  __align__(16) __shared__ f16 xring[2][HH][CC + 8];      // 23,040 B

  for (int idx = tid; idx < 2 * (HH + 2) * (CC + 8); idx += NTHREADS)
    (&hbuf[0][0][0])[idx] = (f16)0.0f;

  const f16* const xTb = xT + (size_t)b * SLICE;
  f16* const sbase = scratch + (size_t)blk * SLICE;

  // global cell offset (units of CC elems) of cell index `cell` on diag dd,
  // clamped into dd's valid range (clamped duplicates are benign).
  auto cellOff = [&](int dd, int cell) -> int {
    const int lo = max(0, dd - (WW - 1));
    const int hi = min(dd, HH - 1);
    const int ipc = min(max(cell, lo), hi);
    const int jp = dd - ipc;
    const int io1 = fi ? (HH - 1 - ipc) : ipc;
    const int jo1 = fj ? (WW - 1 - jp) : jp;
    return io1 * WW + jo1;
  };

  // ---- per-role persistent state (declared in uniform scope) ----
  f16x8 Av[4][2], Ah[4][2];     // compute: gamma A-fragments, all 4 ch-blocks
  f16x8 xb[4];                  // io: x batch for diag d+1 (in flight regs)
  int ucell[4];                 // io: cell index per chunk
  const int cq = quad * 4;
  const int cm = lane >> 3;     // io: cell-in-chunk 0..7
  const int c8 = (lane & 7) * 8;// io: channel offset

  if (wv < NCW) {
    // compute wave: load A fragments. A[m][k]: m=l15, k=quad*8+jj.
#pragma unroll
    for (int cb = 0; cb < 4; ++cb) {
      const int row = cb * 16 + l15;
      const float* pv = gv + row * CC;
      const float* ph = gh + row * CC;
#pragma unroll
      for (int jj = 0; jj < 8; ++jj) {
        Av[cb][0][jj] = (f16)pv[quad * 8 + jj];
        Av[cb][1][jj] = (f16)pv[32 + quad * 8 + jj];
        Ah[cb][0][jj] = (f16)ph[quad * 8 + jj];
        Ah[cb][1][jj] = (f16)ph[32 + quad * 8 + jj];
      }
    }
  } else {
    // io wave: chunk assignment (10 chunks of 8 cells; chunk 9 duplicated
    // across waves — benign: same data, same destinations).
    const int wio = wv - NCW;   // 0..2
#pragma unroll
    for (int k = 0; k < 4; ++k) ucell[k] = min(wio + 3 * k, 9) * 8 + cm;
    // preload diag 0 into ring slot 0 (regs -> ds_write; vmcnt auto-waited)
    f16x8 b0[4];
#pragma unroll
    for (int k = 0; k < 4; ++k)
      b0[k] = *(const f16x8*)(xTb + (cellOff(0, ucell[k]) << 6) + c8);
#pragma unroll
    for (int k = 0; k < 4; ++k)
      *(f16x8*)&xring[0][ucell[k]][c8] = b0[k];
    // preload diag 1 (stays in regs through loop iteration 0)
#pragma unroll
    for (int k = 0; k < 4; ++k)
      xb[k] = *(const f16x8*)(xTb + (cellOff(1, ucell[k]) << 6) + c8);
  }

  __syncthreads();  // zero-init + ring slot 0 visible; one-time full drain

  for (int d = 0; d < NDIAG; ++d) {
    const int p = d & 1, q = p ^ 1;
    const int ilo = max(0, d - (WW - 1));
    const int ihi = min(d, HH - 1);

    if (wv < NCW) {
      // ---------------- compute wave: pure LDS + MFMA ----------------
      const int ntiles = ((ihi - ilo) >> 4) + 1;
      if (wv < ntiles) {                     // wave-uniform
        const int ip  = ilo + wv * 16 + l15;
        const int ipx = min(ip, ihi);        // ring row (clamped, always valid)
        const int su  = min(ip, HH + 1);     // up   (i'-1,j') -> s=i'
        const int sl  = min(ip + 1, HH + 1); // left (i',j'-1) -> s=i'+1
        const f16x8 bu0 = *(const f16x8*)&hbuf[q][su][quad * 8];
        const f16x8 bu1 = *(const f16x8*)&hbuf[q][su][32 + quad * 8];
        const f16x8 bl0 = *(const f16x8*)&hbuf[q][sl][quad * 8];
        const f16x8 bl1 = *(const f16x8*)&hbuf[q][sl][32 + quad * 8];
        const bool ok = (ip <= ihi);
#pragma unroll
        for (int cb = 0; cb < 4; ++cb) {
          const f16x4 xv = *(const f16x4*)&xring[p][ipx][cb * 16 + cq];
          floatx4 a;
          a[0] = (float)xv[0]; a[1] = (float)xv[1];   // seed C with x
          a[2] = (float)xv[2]; a[3] = (float)xv[3];
          a = __builtin_amdgcn_mfma_f32_16x16x32_f16(Av[cb][0], bu0, a, 0, 0, 0);
          a = __builtin_amdgcn_mfma_f32_16x16x32_f16(Av[cb][1], bu1, a, 0, 0, 0);
          a = __builtin_amdgcn_mfma_f32_16x16x32_f16(Ah[cb][0], bl0, a, 0, 0, 0);
          a = __builtin_amdgcn_mfma_f32_16x16x32_f16(Ah[cb][1], bl1, a, 0, 0, 0);
          float h0 = a[0], h1 = a[1], h2 = a[2], h3 = a[3];
          if (do_relu) {
            h0 = fmaxf(h0, 0.f); h1 = fmaxf(h1, 0.f);
            h2 = fmaxf(h2, 0.f); h3 = fmaxf(h3, 0.f);
          }
          f16x4 hw;
          hw[0] = (f16)h0; hw[1] = (f16)h1; hw[2] = (f16)h2; hw[3] = (f16)h3;
          if (ok) *(f16x4*)&hbuf[p][ip + 1][cb * 16 + cq] = hw;
        }
      }
    } else {
      // ---------------- io wave: stream x + flush h ----------------
      // issue loads for diag d+2 (consumed as ds_write next interval)
      f16x8 nb[4];
      const int dpre = min(d + 2, NDIAG - 1);
#pragma unroll
      for (int k = 0; k < 4; ++k)
        nb[k] = *(const f16x8*)(xTb + (cellOff(dpre, ucell[k]) << 6) + c8);
      // write batch (diag d+1, loaded last interval) into slot (d+1)&1
      const int s1 = (d + 1) & 1;
#pragma unroll
      for (int k = 0; k < 4; ++k)
        *(f16x8*)&xring[s1][ucell[k]][c8] = xb[k];
      // flush diag d-1's h: hbuf[q] is read-only during interval d
      if (d >= 1) {
        const int dF = d - 1;
        const int lo = max(0, dF - (WW - 1)), hi = min(dF, HH - 1);
#pragma unroll
        for (int k = 0; k < 4; ++k) {
          const int ipc = min(max(ucell[k], lo), hi);
          const f16x8 hv = *(const f16x8*)&hbuf[q][ipc + 1][c8];
          *(f16x8*)(sbase + (cellOff(dF, ucell[k]) << 6) + c8) = hv;
        }
      }
#pragma unroll
      for (int k = 0; k < 4; ++k) xb[k] = nb[k];
    }

    // Raw barrier: drain LDS only (lgkmcnt(0)); vmem stays in flight.
    __builtin_amdgcn_s_waitcnt(0xC07F);  // vmcnt(63) expcnt(7) lgkmcnt(0)
    __builtin_amdgcn_s_barrier();
  }

  // final flush: diag NDIAG-1 (parity (NDIAG-1)&1 = 0)
  if (wv >= NCW) {
    const int dF = NDIAG - 1;
    const int lo = max(0, dF - (WW - 1)), hi = min(dF, HH - 1);
#pragma unroll
    for (int k = 0; k < 4; ++k) {
      const int ipc = min(max(ucell[k], lo), hi);
      const f16x8 hv = *(const f16x8*)&hbuf[dF & 1][ipc + 1][c8];
      *(f16x8*)(sbase + (cellOff(dF, ucell[k]) << 6) + c8) = hv;
    }
  }
}

// ---------------------------------------------------------------------------
// Reduce: out[b][c][i][j] = sum over 4 dirs of scratch[dir][b][i][j][c].
// ---------------------------------------------------------------------------
__global__ __launch_bounds__(256) void reduce_kernel(const f16* __restrict__ s,
                                                     float* __restrict__ out) {
  const int bi = blockIdx.x;            // b*HH + i
  const int b = bi / HH, i = bi - b * HH;
  __shared__ float tile[WW][CC + 1];    // [j][c], stride 65
  const size_t dstride = (size_t)BB * SLICE;
  const f16* p = s + (size_t)b * SLICE + (size_t)i * (WW * CC);
  for (int idx = threadIdx.x; idx < (WW * CC) / 8; idx += 256) {  // 640
    const int j = idx >> 3, c8 = (idx & 7) * 8;
    const size_t off = (size_t)j * CC + c8;
    const f16x8 a0 = *(const f16x8*)(p + off);
    const f16x8 a1 = *(const f16x8*)(p + off + dstride);
    const f16x8 a2 = *(const f16x8*)(p + off + 2 * dstride);
    const f16x8 a3 = *(const f16x8*)(p + off + 3 * dstride);
#pragma unroll
    for (int k = 0; k < 8; ++k)
      tile[j][c8 + k] = (float)a0[k] + (float)a1[k] + (float)a2[k] + (float)a3[k];
  }
  __syncthreads();
  float* op = out + ((size_t)(b * CC) * HH + i) * WW;  // + c*(H*W) + j
  const int c  = threadIdx.x >> 2;        // 0..63
  const int jb = (threadIdx.x & 3) * 4;   // 0,4,8,12
#pragma unroll
  for (int k = 0; k < 5; ++k) {
    const int j0 = jb + k * 16;
    floatx4 v;
    v[0] = tile[j0 + 0][c];
    v[1] = tile[j0 + 1][c];
    v[2] = tile[j0 + 2][c];
    v[3] = tile[j0 + 3][c];
    *(floatx4*)(op + (size_t)c * (HH * WW) + j0) = v;  // 64B contiguous per 4 lanes
  }
}

// ---------------------------------------------------------------------------
extern "C" void kernel_launch(void* const* d_in, const int* in_sizes, int n_in,
                              void* d_out, int out_size, void* d_ws, size_t ws_size,
                              hipStream_t stream) {
  const float* x = (const float*)d_in[0];
  GPtrs g;
  for (int k = 0; k < 8; ++k) g.p[k] = (const float*)d_in[k + 1];  // g1,g2,g4,g5,g7,g8,g10,g11
  f16* xT = (f16*)d_ws;                         // 26.2 MB
  f16* scratch = xT + (size_t)BB * SLICE;       // 104.9 MB

  xpose_kernel<<<BB * HH, 256, 0, stream>>>(x, xT);
  dag_kernel<<<4 * BB, NTHREADS, 0, stream>>>((const f16*)xT, g, scratch);
  reduce_kernel<<<BB * HH, 256, 0, stream>>>((const f16*)scratch, (float*)d_out);
}